// Round 1
// baseline (902.017 us; speedup 1.0000x reference)
//
#include <hip/hip_runtime.h>
#include <math.h>

#define D 512
#define STEPS 6
#define MAXB1 1024

__device__ __forceinline__ float wave_reduce_sum(float v) {
#pragma unroll
    for (int off = 32; off > 0; off >>= 1) v += __shfl_xor(v, off);
    return v;
}

__device__ __forceinline__ float dot8(const float4& a, const float4& b,
                                      const float4& ha, const float4& hb) {
    return a.x*ha.x + a.y*ha.y + a.z*ha.z + a.w*ha.w
         + b.x*hb.x + b.y*hb.y + b.z*hb.z + b.w*hb.w;
}

// online-softmax update: (m, s, va, vb) running state; d = score, (a,b) = row data
#define ONLINE(dv, av, bv) do {                                          \
    if ((dv) > m) {                                                      \
        float sc_ = __expf(m - (dv));                                    \
        s *= sc_;                                                        \
        va.x *= sc_; va.y *= sc_; va.z *= sc_; va.w *= sc_;              \
        vb.x *= sc_; vb.y *= sc_; vb.z *= sc_; vb.w *= sc_;              \
        m = (dv);                                                        \
    }                                                                    \
    float w_ = __expf((dv) - m);                                         \
    s += w_;                                                             \
    va.x += w_*(av).x; va.y += w_*(av).y; va.z += w_*(av).z; va.w += w_*(av).w; \
    vb.x += w_*(bv).x; vb.y += w_*(bv).y; vb.z += w_*(bv).z; vb.w += w_*(bv).w; \
} while (0)

// Pass over x: per-block online softmax partials (m, s, v[512])
__global__ __launch_bounds__(256, 4) void attn_kernel(
    const float* __restrict__ x, const float* __restrict__ h,
    float* __restrict__ pm, float* __restrict__ ps, float* __restrict__ pv, int N)
{
    __shared__ float h_s[D];
    __shared__ float red_v[4][D];
    __shared__ float red_ms[8];
    for (int i = threadIdx.x; i < D; i += 256) h_s[i] = h[i];
    __syncthreads();

    const int wave = threadIdx.x >> 6, lane = threadIdx.x & 63;
    const int nw = gridDim.x << 2;              // total waves
    const float4 ha = ((const float4*)h_s)[lane];
    const float4 hb = ((const float4*)h_s)[64 + lane];

    float m = -1e30f, s = 0.f;
    float4 va = make_float4(0.f, 0.f, 0.f, 0.f);
    float4 vb = make_float4(0.f, 0.f, 0.f, 0.f);

    int i = (blockIdx.x << 2) + wave;
    const int limit4 = N - 3 * nw;
    for (; i < limit4; i += (nw << 2)) {
        const float4* x0 = (const float4*)(x + (size_t)i * D);
        const float4* x1 = (const float4*)(x + (size_t)(i + nw) * D);
        const float4* x2 = (const float4*)(x + (size_t)(i + 2 * nw) * D);
        const float4* x3 = (const float4*)(x + (size_t)(i + 3 * nw) * D);
        float4 a0 = x0[lane], b0 = x0[64 + lane];
        float4 a1 = x1[lane], b1 = x1[64 + lane];
        float4 a2 = x2[lane], b2 = x2[64 + lane];
        float4 a3 = x3[lane], b3 = x3[64 + lane];
        float d0 = dot8(a0, b0, ha, hb);
        float d1 = dot8(a1, b1, ha, hb);
        float d2 = dot8(a2, b2, ha, hb);
        float d3 = dot8(a3, b3, ha, hb);
#pragma unroll
        for (int off = 32; off > 0; off >>= 1) {
            d0 += __shfl_xor(d0, off);
            d1 += __shfl_xor(d1, off);
            d2 += __shfl_xor(d2, off);
            d3 += __shfl_xor(d3, off);
        }
        ONLINE(d0, a0, b0);
        ONLINE(d1, a1, b1);
        ONLINE(d2, a2, b2);
        ONLINE(d3, a3, b3);
    }
    for (; i < N; i += nw) {
        const float4* x0 = (const float4*)(x + (size_t)i * D);
        float4 a0 = x0[lane], b0 = x0[64 + lane];
        float d0 = dot8(a0, b0, ha, hb);
        d0 = wave_reduce_sum(d0);
        ONLINE(d0, a0, b0);
    }

    // combine the 4 waves of this block
    ((float4*)red_v[wave])[lane] = va;
    ((float4*)red_v[wave])[64 + lane] = vb;
    if (lane == 0) { red_ms[wave] = m; red_ms[4 + wave] = s; }
    __syncthreads();

    float m0 = red_ms[0], m1 = red_ms[1], m2 = red_ms[2], m3 = red_ms[3];
    float bm = fmaxf(fmaxf(m0, m1), fmaxf(m2, m3));
    float sc0 = __expf(m0 - bm), sc1 = __expf(m1 - bm);
    float sc2 = __expf(m2 - bm), sc3 = __expf(m3 - bm);
    if (threadIdx.x == 0) {
        pm[blockIdx.x] = bm;
        ps[blockIdx.x] = red_ms[4]*sc0 + red_ms[5]*sc1 + red_ms[6]*sc2 + red_ms[7]*sc3;
    }
    const int t = threadIdx.x;
    float v0 = red_v[0][t]*sc0 + red_v[1][t]*sc1 + red_v[2][t]*sc2 + red_v[3][t]*sc3;
    float v1 = red_v[0][t+256]*sc0 + red_v[1][t+256]*sc1
             + red_v[2][t+256]*sc2 + red_v[3][t+256]*sc3;
    pv[(size_t)blockIdx.x * D + t] = v0;
    pv[(size_t)blockIdx.x * D + t + 256] = v1;
}

// Reduce B1 partials -> ctx[512]; also store into contexts[t]
__global__ __launch_bounds__(256) void combine_kernel(
    const float* __restrict__ pm, const float* __restrict__ ps,
    const float* __restrict__ pv, float* __restrict__ ctx,
    float* __restrict__ ctx_store, int B1)
{
    __shared__ float sm[MAXB1];
    __shared__ float red[8];
    __shared__ float pr[4][64];
    const int tid = threadIdx.x, lane = tid & 63, wave = tid >> 6;

    float lm = -1e30f;
    for (int b = tid; b < B1; b += 256) lm = fmaxf(lm, pm[b]);
#pragma unroll
    for (int off = 32; off > 0; off >>= 1) lm = fmaxf(lm, __shfl_xor(lm, off));
    if (lane == 0) red[wave] = lm;
    __syncthreads();
    float M = fmaxf(fmaxf(red[0], red[1]), fmaxf(red[2], red[3]));

    float lS = 0.f;
    for (int b = tid; b < B1; b += 256) {
        float e = __expf(pm[b] - M);
        sm[b] = e;
        lS += ps[b] * e;
    }
#pragma unroll
    for (int off = 32; off > 0; off >>= 1) lS += __shfl_xor(lS, off);
    if (lane == 0) red[4 + wave] = lS;
    __syncthreads();
    float S = red[4] + red[5] + red[6] + red[7];

    const int d = (blockIdx.x << 6) + lane;
    float acc = 0.f;
    for (int b = wave; b < B1; b += 4)
        acc += pv[(size_t)b * D + d] * sm[b];
    pr[wave][lane] = acc;
    __syncthreads();
    if (tid < 64) {
        float v = (pr[0][lane] + pr[1][lane] + pr[2][lane] + pr[3][lane]) / S;
        int dd = (blockIdx.x << 6) + lane;
        ctx[dd] = v;
        ctx_store[dd] = v;
    }
}

// One block per output j: 4 gate-row dots (wave each) + cell update.
// h double-buffered (h_in read by all blocks, h_out written per-j).
__global__ __launch_bounds__(256) void lstm_kernel(
    const float* __restrict__ W_ih, const float* __restrict__ W_hh,
    const float* __restrict__ b_ih, const float* __restrict__ b_hh,
    const float* __restrict__ ctx, const float* __restrict__ h_in,
    float* __restrict__ h_out, float* __restrict__ c)
{
    __shared__ float inp[2 * D];   // [ctx ; h]
    __shared__ float gate[4];
    const int tid = threadIdx.x, lane = tid & 63, g = tid >> 6;
    const int j = blockIdx.x;
    for (int i = tid; i < D; i += 256) { inp[i] = ctx[i]; inp[D + i] = h_in[i]; }
    __syncthreads();

    const int row = (g << 9) + j;   // gate order i,f,g,o = rows 0..511, 512.., ...
    const float4* wr = (const float4*)(W_ih + (size_t)row * (2 * D));
    float dot = 0.f;
#pragma unroll
    for (int q = 0; q < 4; ++q) {
        float4 w4 = wr[lane + (q << 6)];
        float4 i4 = ((const float4*)inp)[lane + (q << 6)];
        dot += w4.x*i4.x + w4.y*i4.y + w4.z*i4.z + w4.w*i4.w;
    }
    const float4* wr2 = (const float4*)(W_hh + (size_t)row * D);
#pragma unroll
    for (int q = 0; q < 2; ++q) {
        float4 w4 = wr2[lane + (q << 6)];
        float4 i4 = ((const float4*)(inp + D))[lane + (q << 6)];
        dot += w4.x*i4.x + w4.y*i4.y + w4.z*i4.z + w4.w*i4.w;
    }
    dot = wave_reduce_sum(dot);
    if (lane == 0) gate[g] = dot + b_ih[row] + b_hh[row];
    __syncthreads();
    if (tid == 0) {
        float ig = 1.f / (1.f + __expf(-gate[0]));
        float fg = 1.f / (1.f + __expf(-gate[1]));
        float gg = tanhf(gate[2]);
        float og = 1.f / (1.f + __expf(-gate[3]));
        float cn = fg * c[j] + ig * gg;
        c[j] = cn;
        h_out[j] = og * tanhf(cn);
    }
}

// logits = W_proj @ concat(contexts) + b_proj ; 4 rows per block (wave each)
__global__ __launch_bounds__(256) void proj_kernel(
    const float* __restrict__ W_proj, const float* __restrict__ b_proj,
    const float* __restrict__ ctxs, float* __restrict__ logits)
{
    __shared__ float cc[STEPS * D];   // 3072 floats
    const int tid = threadIdx.x, lane = tid & 63, g = tid >> 6;
    for (int i = tid; i < STEPS * D; i += 256) cc[i] = ctxs[i];
    __syncthreads();

    const int row = (blockIdx.x << 2) + g;
    const float4* wr = (const float4*)(W_proj + (size_t)row * (STEPS * D));
    float dot = 0.f;
#pragma unroll
    for (int q = 0; q < 12; ++q) {
        float4 w4 = wr[lane + (q << 6)];
        float4 i4 = ((const float4*)cc)[lane + (q << 6)];
        dot += w4.x*i4.x + w4.y*i4.y + w4.z*i4.z + w4.w*i4.w;
    }
    dot = wave_reduce_sum(dot);
    if (lane == 0) logits[row] = dot + b_proj[row];
}

__global__ void softmax512_kernel(const float* __restrict__ logits, float* __restrict__ out)
{
    __shared__ float red[8];
    const int tid = threadIdx.x, lane = tid & 63, wave = tid >> 6;
    float v = logits[tid];
    float m = v;
#pragma unroll
    for (int off = 32; off > 0; off >>= 1) m = fmaxf(m, __shfl_xor(m, off));
    if (lane == 0) red[wave] = m;
    __syncthreads();
    m = red[0];
#pragma unroll
    for (int k = 1; k < 8; ++k) m = fmaxf(m, red[k]);
    __syncthreads();
    float e = __expf(v - m);
    float s = e;
#pragma unroll
    for (int off = 32; off > 0; off >>= 1) s += __shfl_xor(s, off);
    if (lane == 0) red[wave] = s;
    __syncthreads();
    s = 0.f;
#pragma unroll
    for (int k = 0; k < 8; ++k) s += red[k];
    out[tid] = e / s;
}

extern "C" void kernel_launch(void* const* d_in, const int* in_sizes, int n_in,
                              void* d_out, int out_size, void* d_ws, size_t ws_size,
                              hipStream_t stream)
{
    const float* x      = (const float*)d_in[0];
    const float* W_ih   = (const float*)d_in[1];
    const float* W_hh   = (const float*)d_in[2];
    const float* b_ih   = (const float*)d_in[3];
    const float* b_hh   = (const float*)d_in[4];
    const float* W_proj = (const float*)d_in[5];
    const float* b_proj = (const float*)d_in[6];
    const int N = in_sizes[0] / D;

    float* ws     = (float*)d_ws;
    float* hbuf   = ws;           // 2*512 (double-buffered h)
    float* c      = ws + 1024;    // 512
    float* ctx    = ws + 1536;    // 512
    float* ctxs   = ws + 2048;    // 6*512
    float* logits = ws + 5120;    // 512
    const size_t base = 5632;
    int B1 = MAXB1;
    if ((base + (size_t)B1 * (D + 2)) * sizeof(float) > ws_size) {
        B1 = (int)((ws_size / sizeof(float) - base) / (D + 2));
        if (B1 > MAXB1) B1 = MAXB1;
        if (B1 < 8) B1 = 8;
    }
    float* pm = ws + base;
    float* ps = pm + B1;
    float* pv = ps + B1;

    // zero h[0], h[1], c  (ws is re-poisoned before every timed launch)
    hipMemsetAsync(d_ws, 0, 1536 * sizeof(float), stream);

    for (int t = 0; t < STEPS; ++t) {
        float* h_in  = hbuf + ((t & 1) << 9);
        float* h_out = hbuf + (((t + 1) & 1) << 9);
        attn_kernel<<<B1, 256, 0, stream>>>(x, h_in, pm, ps, pv, N);
        combine_kernel<<<8, 256, 0, stream>>>(pm, ps, pv, ctx, ctxs + t * D, B1);
        lstm_kernel<<<512, 256, 0, stream>>>(W_ih, W_hh, b_ih, b_hh, ctx, h_in, h_out, c);
    }
    proj_kernel<<<128, 256, 0, stream>>>(W_proj, b_proj, ctxs, logits);
    softmax512_kernel<<<1, 512, 0, stream>>>(logits, (float*)d_out);
}